// Round 5
// baseline (462.059 us; speedup 1.0000x reference)
//
#include <hip/hip_runtime.h>
#include <hip/hip_bf16.h>

typedef short bf16x8 __attribute__((ext_vector_type(8)));
typedef float f32x4 __attribute__((ext_vector_type(4)));

#define HID 256
#define IN_DIM 128
#define M_BLOCK 64
#define LDS_STRIDE 264   // ushorts; 132 dwords/row, 132%32=4 spreads banks across rows

__device__ __forceinline__ float bf2f(unsigned short x) {
    union { unsigned int u; float f; } c; c.u = ((unsigned int)x) << 16; return c.f;
}
__device__ __forceinline__ unsigned short f2bf(float f) {
    union { float f; unsigned int u; } c; c.f = f;
    unsigned int u = c.u;
    u += 0x7FFFu + ((u >> 16) & 1u);   // RNE
    return (unsigned short)(u >> 16);
}
__device__ __forceinline__ unsigned int pack2(float lo, float hi) {
    return (unsigned int)f2bf(lo) | ((unsigned int)f2bf(hi) << 16);
}

// Runtime dtype guards (validated in R4: all float tensors detected fp32,
// indices int32 — kept as cheap insurance, they cost a few L2-hot loads).
__device__ __forceinline__ bool detect_bf16(const unsigned short* p, int strideElems) {
    const int lane = threadIdx.x & 63;
    unsigned int u = p[(size_t)2 * lane * strideElems];
    unsigned int e = (u >> 7) & 0xFFu;
    bool bad = ((u & 0x7FFFu) != 0u) && (e < 90u || e > 141u);
    return __ballot(bad) == 0ull;
}
__device__ __forceinline__ bool detect_idx64(const int* p) {
    const int lane = threadIdx.x & 63;
    int v = p[2 * (lane * 64) + 1];
    return __ballot(v != 0) == 0ull;
}

// Pack W1 [256 k][256 n] row-major (fp32 or bf16) into bf16 B-fragment order:
// packed[kt][nt][lane][j] = bf16(W1[kt*32 + (lane>>4)*8 + j][nt*16 + (lane&15)])
extern "C" __global__ void pack_w1_kernel(
    const void* __restrict__ W1c,
    const void* __restrict__ W1b,
    unsigned short* __restrict__ outp)
{
    const int t = blockIdx.y;
    const void* W1 = t ? W1b : W1c;
    const unsigned short* W1u = (const unsigned short*)W1;
    const float* W1f = (const float*)W1;
    const bool w1bf = detect_bf16(W1u, 512);

    const int tid = blockIdx.x * 256 + threadIdx.x;   // 0..8191
    const int lane = tid & 63;
    const int nt = (tid >> 6) & 15;
    const int kt = tid >> 10;
    const int k0 = kt * 32 + (lane >> 4) * 8;
    const int n  = nt * 16 + (lane & 15);
    unsigned short vals[8];
#pragma unroll
    for (int j = 0; j < 8; ++j) {
        const int src = (k0 + j) * HID + n;
        vals[j] = w1bf ? W1u[src] : f2bf(W1f[src]);
    }
    unsigned short* dst = outp + (size_t)t * 65536 + (size_t)tid * 8;
    *reinterpret_cast<uint4*>(dst) = *reinterpret_cast<const uint4*>(vals);
}

extern "C" __global__ __launch_bounds__(256, 3)
void edge_mlp_kernel(
    const void* __restrict__ user_embed,
    const void* __restrict__ item_embed,
    const int* __restrict__ u0, const int* __restrict__ v0,
    const int* __restrict__ u1, const int* __restrict__ v1,
    const unsigned short* __restrict__ packedW1,
    const void* __restrict__ b1_0, const void* __restrict__ w2_0,
    const void* __restrict__ b2_0,
    const void* __restrict__ b1_1, const void* __restrict__ w2_1,
    const void* __restrict__ b2_1,
    float* __restrict__ out, int E)           // <-- fp32 output (reference returns float32)
{
    __shared__ unsigned short sA[M_BLOCK * LDS_STRIDE];
    __shared__ float pRed[4][M_BLOCK];

    const int t  = blockIdx.y;
    const int e0 = blockIdx.x * M_BLOCK;
    const int tid = threadIdx.x;

    const int* uI = t ? u1 : u0;
    const int* vI = t ? v1 : v0;
    const void* b1 = t ? b1_1 : b1_0;
    const void* w2 = t ? w2_1 : w2_0;
    const void* b2 = t ? b2_1 : b2_0;
    const unsigned short* pW = packedW1 + (size_t)t * 65536;

    const bool uBf  = detect_bf16((const unsigned short*)user_embed, 1024);
    const bool iBf  = detect_bf16((const unsigned short*)item_embed, 1024);
    const bool w2Bf = detect_bf16((const unsigned short*)w2, 2);
    const bool u64f = detect_idx64(uI);
    const bool v64f = detect_idx64(vI);

    // ---- gather 64 edges x 256 values -> bf16 LDS (4 threads/edge) ----
    {
        const int el = tid >> 2;
        const int q  = tid & 3;          // quarter of concat row: k in [64q, 64q+64)
        const int e  = e0 + el;
        uint4* dst = reinterpret_cast<uint4*>(&sA[el * LDS_STRIDE + q * 64]);
        if (e < E) {
            size_t idx; const void* tab; bool tbf; int off;
            if (q < 2) { idx = (size_t)(u64f ? uI[2 * e] : uI[e]); tab = user_embed; tbf = uBf; off = q * 64; }
            else       { idx = (size_t)(v64f ? vI[2 * e] : vI[e]); tab = item_embed; tbf = iBf; off = (q - 2) * 64; }
            if (tbf) {
                const uint4* s4 = reinterpret_cast<const uint4*>(
                    (const unsigned short*)tab + idx * IN_DIM + off);
#pragma unroll
                for (int i = 0; i < 8; ++i) dst[i] = s4[i];
            } else {
                const float4* s4 = reinterpret_cast<const float4*>(
                    (const float*)tab + idx * IN_DIM + off);
#pragma unroll
                for (int i = 0; i < 8; ++i) {
                    float4 f0 = s4[2 * i];
                    float4 f1 = s4[2 * i + 1];
                    uint4 o;
                    o.x = pack2(f0.x, f0.y);
                    o.y = pack2(f0.z, f0.w);
                    o.z = pack2(f1.x, f1.y);
                    o.w = pack2(f1.z, f1.w);
                    dst[i] = o;
                }
            }
        } else {
            uint4 z; z.x = z.y = z.z = z.w = 0;
#pragma unroll
            for (int i = 0; i < 8; ++i) dst[i] = z;
        }
    }
    __syncthreads();

    const int wv   = tid >> 6;    // wave owns n-tiles wv*4 .. wv*4+3
    const int lane = tid & 63;
    const int lq   = lane >> 4;
    const int lm   = lane & 15;

    f32x4 acc[4][4];
#pragma unroll
    for (int ms = 0; ms < 4; ++ms)
#pragma unroll
        for (int ntg = 0; ntg < 4; ++ntg)
            acc[ms][ntg] = (f32x4){0.f, 0.f, 0.f, 0.f};

#pragma unroll
    for (int kt = 0; kt < 8; ++kt) {
        const int koff = kt * 32 + lq * 8;
        bf16x8 aF[4];
#pragma unroll
        for (int ms = 0; ms < 4; ++ms)
            aF[ms] = *reinterpret_cast<const bf16x8*>(&sA[(ms * 16 + lm) * LDS_STRIDE + koff]);
#pragma unroll
        for (int ntg = 0; ntg < 4; ++ntg) {
            const int nt = wv * 4 + ntg;
            bf16x8 bF = *reinterpret_cast<const bf16x8*>(
                pW + (((size_t)(kt * 16 + nt) * 64 + lane) * 8));
#pragma unroll
            for (int ms = 0; ms < 4; ++ms)
                acc[ms][ntg] = __builtin_amdgcn_mfma_f32_16x16x32_bf16(aF[ms], bF, acc[ms][ntg], 0, 0, 0);
        }
    }

    // ---- fused epilogue (fp32): relu(acc + b1) . w2, shuffle-reduce ----
    float part[4][4];
#pragma unroll
    for (int ms = 0; ms < 4; ++ms)
#pragma unroll
        for (int r = 0; r < 4; ++r) part[ms][r] = 0.f;

#pragma unroll
    for (int ntg = 0; ntg < 4; ++ntg) {
        const int n = (wv * 4 + ntg) * 16 + lm;
        const float b1n = w2Bf ? bf2f(((const unsigned short*)b1)[n]) : ((const float*)b1)[n];
        const float w2n = w2Bf ? bf2f(((const unsigned short*)w2)[n]) : ((const float*)w2)[n];
#pragma unroll
        for (int ms = 0; ms < 4; ++ms)
#pragma unroll
            for (int r = 0; r < 4; ++r) {
                float h = acc[ms][ntg][r] + b1n;
                h = fmaxf(h, 0.f);
                part[ms][r] = fmaf(h, w2n, part[ms][r]);
            }
    }

#pragma unroll
    for (int off = 1; off < 16; off <<= 1) {
#pragma unroll
        for (int ms = 0; ms < 4; ++ms)
#pragma unroll
            for (int r = 0; r < 4; ++r)
                part[ms][r] += __shfl_xor(part[ms][r], off, 64);
    }

    if (lm == 0) {
#pragma unroll
        for (int ms = 0; ms < 4; ++ms)
#pragma unroll
            for (int r = 0; r < 4; ++r)
                pRed[wv][ms * 16 + lq * 4 + r] = part[ms][r];
    }
    __syncthreads();

    if (tid < M_BLOCK) {
        const int e = e0 + tid;
        if (e < E) {
            const float b2v = w2Bf ? bf2f(((const unsigned short*)b2)[0]) : ((const float*)b2)[0];
            float s = b2v + pRed[0][tid] + pRed[1][tid] + pRed[2][tid] + pRed[3][tid];
            out[(size_t)t * E + e] = s;      // fp32 store
        }
    }
}

extern "C" void kernel_launch(void* const* d_in, const int* in_sizes, int n_in,
                              void* d_out, int out_size, void* d_ws, size_t ws_size,
                              hipStream_t stream)
{
    const void* user_embed = d_in[0];
    const void* item_embed = d_in[1];
    const int* u0 = (const int*)d_in[2];
    const int* v0 = (const int*)d_in[3];
    const int* u1 = (const int*)d_in[4];
    const int* v1 = (const int*)d_in[5];
    const void* W1c = d_in[6];
    const void* b1c = d_in[7];
    const void* w2c = d_in[8];
    const void* b2c = d_in[9];
    const void* W1b = d_in[10];
    const void* b1b = d_in[11];
    const void* w2b = d_in[12];
    const void* b2b = d_in[13];

    const int E = in_sizes[2];
    unsigned short* packedW1 = (unsigned short*)d_ws;   // 256 KB

    hipLaunchKernelGGL(pack_w1_kernel, dim3(32, 2), dim3(256), 0, stream, W1c, W1b, packedW1);

    dim3 grid((E + M_BLOCK - 1) / M_BLOCK, 2);
    hipLaunchKernelGGL(edge_mlp_kernel, grid, dim3(256), 0, stream,
                       user_embed, item_embed, u0, v0, u1, v1, packedW1,
                       b1c, w2c, b2c, b1b, w2b, b2b,
                       (float*)d_out, E);
}